// Round 3
// baseline (748.303 us; speedup 1.0000x reference)
//
#include <hip/hip_runtime.h>
#include <math.h>

#define B_    128
#define S_    2048
#define FEAT_ 512
#define DK_   64
#define NSPLIT 32
#define CHUNK  (S_ / NSPLIT)   // 64 rows per split

// ---------------------------------------------------------------------------
// Kernel 1: v[b,f] = sum_d W_K[f,d] * (sum_g input_q[b,g] * W_Q[g,d])
// One block per batch. Also zeroes the per-batch done-counter for kernel 2.
// ---------------------------------------------------------------------------
__global__ __launch_bounds__(256) void qv_kernel(
    const float* __restrict__ input_q, const float* __restrict__ W_Q,
    const float* __restrict__ W_K, float* __restrict__ v,
    unsigned* __restrict__ cnt) {
  int b = blockIdx.x;
  int tid = threadIdx.x;
  if (tid == 0) cnt[b] = 0u;   // visible to pass_kernel via stream order
  __shared__ float xq[FEAT_];
  __shared__ float part[4][DK_];
  __shared__ float qs[DK_];
  for (int f = tid; f < FEAT_; f += 256) xq[f] = input_q[b * FEAT_ + f];
  __syncthreads();
  {
    int d = tid & 63, c = tid >> 6;           // 4 chunks of 128 features
    float s = 0.f;
    int f0 = c * 128;
    for (int f = f0; f < f0 + 128; ++f) s = fmaf(xq[f], W_Q[f * DK_ + d], s);
    part[c][d] = s;
  }
  __syncthreads();
  if (tid < DK_)
    qs[tid] = part[0][tid] + part[1][tid] + part[2][tid] + part[3][tid];
  __syncthreads();
  for (int f = tid; f < FEAT_; f += 256) {
    const float4* wk = (const float4*)(W_K + f * DK_);
    float s = 0.f;
#pragma unroll
    for (int d4 = 0; d4 < DK_ / 4; ++d4) {
      float4 w = wk[d4];
      s = fmaf(w.x, qs[d4 * 4 + 0], s);
      s = fmaf(w.y, qs[d4 * 4 + 1], s);
      s = fmaf(w.z, qs[d4 * 4 + 2], s);
      s = fmaf(w.w, qs[d4 * 4 + 3], s);
    }
    v[b * FEAT_ + f] = s;
  }
}

__device__ __forceinline__ float dot8(float4 x0, float4 x1, float4 v0, float4 v1) {
  float p = x0.x * v0.x;
  p = fmaf(x0.y, v0.y, p);
  p = fmaf(x0.z, v0.z, p);
  p = fmaf(x0.w, v0.w, p);
  p = fmaf(x1.x, v1.x, p);
  p = fmaf(x1.y, v1.y, p);
  p = fmaf(x1.z, v1.z, p);
  p = fmaf(x1.w, v1.w, p);
  return p;
}

// ---------------------------------------------------------------------------
// Kernel 2: streaming pass with online softmax; software-pipelined (depth-1
// prefetch of the next 4-row group). Per-(b,split) partials to ws. The last
// block of each batch (atomic counter) performs the combine + output write.
// ---------------------------------------------------------------------------
__global__ __launch_bounds__(256) void pass_kernel(
    const float* __restrict__ input_k, const int* __restrict__ ctx,
    const float* __restrict__ v, float* __restrict__ pm,
    float* __restrict__ pl, float* __restrict__ pacc,
    unsigned* __restrict__ cnt, float* __restrict__ out) {
  int split = blockIdx.x;
  int b = blockIdx.y;
  int L = ctx[b];
  int s0 = split * CHUNK;
  int s1 = min(s0 + CHUNK, L);
  int tid = threadIdx.x, wave = tid >> 6, lane = tid & 63;
  int idx = b * NSPLIT + split;

  if (s0 < L) {
    const float* vb = v + b * FEAT_;
    float4 v0 = *(const float4*)(vb + lane * 4);
    float4 v1 = *(const float4*)(vb + 256 + lane * 4);

    float m = -INFINITY, l = 0.f;
    float4 a0 = make_float4(0.f, 0.f, 0.f, 0.f);
    float4 a1 = make_float4(0.f, 0.f, 0.f, 0.f);

    const float* base = input_k + (size_t)b * S_ * FEAT_;
    int sbase = s0 + wave;
    int r = s1 - sbase;                         // rows available (stride 4)
    int ng = (r >= 13) ? ((r - 13) >> 4) + 1 : 0;  // full 4-row groups

    float4 c0, c1, c2, c3, c4, c5, c6, c7;
    float4 n0, n1, n2, n3, n4, n5, n6, n7;

#define LOADG(d0, d1, d2, d3, d4, d5, d6, d7, srow)                 \
    {                                                               \
      const float* r_ = base + (size_t)(srow) * FEAT_ + lane * 4;   \
      d0 = *(const float4*)(r_);                                    \
      d1 = *(const float4*)(r_ + 256);                              \
      d2 = *(const float4*)(r_ + 4 * FEAT_);                        \
      d3 = *(const float4*)(r_ + 4 * FEAT_ + 256);                  \
      d4 = *(const float4*)(r_ + 8 * FEAT_);                        \
      d5 = *(const float4*)(r_ + 8 * FEAT_ + 256);                  \
      d6 = *(const float4*)(r_ + 12 * FEAT_);                       \
      d7 = *(const float4*)(r_ + 12 * FEAT_ + 256);                 \
    }

    if (ng > 0) LOADG(c0, c1, c2, c3, c4, c5, c6, c7, sbase);
    for (int g = 0; g < ng; ++g) {
      if (g + 1 < ng)
        LOADG(n0, n1, n2, n3, n4, n5, n6, n7, sbase + 16 * (g + 1));
      float p0 = dot8(c0, c1, v0, v1);
      float p1 = dot8(c2, c3, v0, v1);
      float p2 = dot8(c4, c5, v0, v1);
      float p3 = dot8(c6, c7, v0, v1);
#pragma unroll
      for (int off = 32; off; off >>= 1) {
        p0 += __shfl_xor(p0, off, 64);
        p1 += __shfl_xor(p1, off, 64);
        p2 += __shfl_xor(p2, off, 64);
        p3 += __shfl_xor(p3, off, 64);
      }
      float mn = fmaxf(fmaxf(fmaxf(p0, p1), fmaxf(p2, p3)), m);
      float sc = __expf(m - mn);   // first group: exp(-inf)=0
      float w0 = __expf(p0 - mn), w1 = __expf(p1 - mn);
      float w2 = __expf(p2 - mn), w3 = __expf(p3 - mn);
      l = fmaf(l, sc, (w0 + w1) + (w2 + w3));
#define ACC(comp, f0c, f1c, f2c, f3c)                       \
      {                                                      \
        float t = comp * sc;                                 \
        t = fmaf(w0, f0c, t);                                \
        t = fmaf(w1, f1c, t);                                \
        t = fmaf(w2, f2c, t);                                \
        t = fmaf(w3, f3c, t);                                \
        comp = t;                                            \
      }
      ACC(a0.x, c0.x, c2.x, c4.x, c6.x)
      ACC(a0.y, c0.y, c2.y, c4.y, c6.y)
      ACC(a0.z, c0.z, c2.z, c4.z, c6.z)
      ACC(a0.w, c0.w, c2.w, c4.w, c6.w)
      ACC(a1.x, c1.x, c3.x, c5.x, c7.x)
      ACC(a1.y, c1.y, c3.y, c5.y, c7.y)
      ACC(a1.z, c1.z, c3.z, c5.z, c7.z)
      ACC(a1.w, c1.w, c3.w, c5.w, c7.w)
#undef ACC
      m = mn;
      if (g + 1 < ng) {
        c0 = n0; c1 = n1; c2 = n2; c3 = n3;
        c4 = n4; c5 = n5; c6 = n6; c7 = n7;
      }
    }

    // tail: single row per step
    for (int s = sbase + 16 * ng; s < s1; s += 4) {
      const float* row = base + (size_t)s * FEAT_;
      float4 x0 = *(const float4*)(row + lane * 4);
      float4 x1 = *(const float4*)(row + 256 + lane * 4);
      float p = dot8(x0, x1, v0, v1);
#pragma unroll
      for (int off = 32; off; off >>= 1) p += __shfl_xor(p, off, 64);
      float mn = fmaxf(m, p);
      float sc = __expf(m - mn);
      float w = __expf(p - mn);
      l = fmaf(l, sc, w);
      a0.x = fmaf(w, x0.x, a0.x * sc);
      a0.y = fmaf(w, x0.y, a0.y * sc);
      a0.z = fmaf(w, x0.z, a0.z * sc);
      a0.w = fmaf(w, x0.w, a0.w * sc);
      a1.x = fmaf(w, x1.x, a1.x * sc);
      a1.y = fmaf(w, x1.y, a1.y * sc);
      a1.z = fmaf(w, x1.z, a1.z * sc);
      a1.w = fmaf(w, x1.w, a1.w * sc);
      m = mn;
    }

    // cross-wave combine in LDS
    __shared__ float sm[4], sl[4];
    __shared__ float sa[4][FEAT_];
    if (lane == 0) { sm[wave] = m; sl[wave] = l; }
    *(float4*)&sa[wave][lane * 4] = a0;
    *(float4*)&sa[wave][256 + lane * 4] = a1;
    __syncthreads();

    float M = fmaxf(fmaxf(sm[0], sm[1]), fmaxf(sm[2], sm[3]));
    float e0 = __expf(sm[0] - M), e1 = __expf(sm[1] - M);
    float e2 = __expf(sm[2] - M), e3 = __expf(sm[3] - M);
    if (tid == 0) {
      pm[idx] = M;
      pl[idx] = e0 * sl[0] + e1 * sl[1] + e2 * sl[2] + e3 * sl[3];
    }
    for (int f = tid; f < FEAT_; f += 256)
      pacc[(size_t)idx * FEAT_ + f] =
          e0 * sa[0][f] + e1 * sa[1][f] + e2 * sa[2][f] + e3 * sa[3][f];
  } else {
    // inactive split: no pacc write (combine will skip e==0 splits)
    if (tid == 0) { pm[idx] = -INFINITY; pl[idx] = 0.f; }
  }

  // ------- last-block-per-batch combine -------
  __threadfence();                       // release our pm/pl/pacc writes
  __shared__ unsigned last;
  if (tid == 0) last = atomicAdd(&cnt[b], 1u);
  __syncthreads();
  if (last == NSPLIT - 1) {
    __threadfence();                     // acquire other blocks' writes
    __shared__ float e[NSPLIT];
    __shared__ float inv_s;
    if (tid < NSPLIT) {                  // lanes 0..31 of wave 0
      float mi = pm[b * NSPLIT + tid];
      float M = mi;
#pragma unroll
      for (int off = 16; off; off >>= 1) M = fmaxf(M, __shfl_xor(M, off, 64));
      float ei = (M == -INFINITY) ? 0.f : __expf(mi - M);
      e[tid] = ei;
      float lw = ei * pl[b * NSPLIT + tid];
#pragma unroll
      for (int off = 16; off; off >>= 1) lw += __shfl_xor(lw, off, 64);
      if (tid == 0) inv_s = (lw > 0.f) ? 1.f / lw : 0.f;  // L==0 -> zeros
    }
    __syncthreads();
    float inv = inv_s;
    for (int f = tid; f < FEAT_; f += 256) {
      float s = 0.f;
      for (int i = 0; i < NSPLIT; ++i)
        if (e[i] > 0.f)                  // block-uniform branch, skips loads
          s = fmaf(e[i], pacc[((size_t)(b * NSPLIT + i)) * FEAT_ + f], s);
      out[b * FEAT_ + f] = s * inv;
    }
  }
}

extern "C" void kernel_launch(void* const* d_in, const int* in_sizes, int n_in,
                              void* d_out, int out_size, void* d_ws, size_t ws_size,
                              hipStream_t stream) {
  const float* input_k = (const float*)d_in[0];
  const float* input_q = (const float*)d_in[1];
  const int*   ctx     = (const int*)d_in[2];
  const float* W_K     = (const float*)d_in[3];
  const float* W_Q     = (const float*)d_in[4];
  float* out = (float*)d_out;

  char* ws = (char*)d_ws;
  float* v    = (float*)ws;                                   // B*FEAT
  float* pm   = (float*)(ws + (size_t)B_ * FEAT_ * sizeof(float));
  float* pl   = pm + B_ * NSPLIT;
  float* pacc = pl + B_ * NSPLIT;                             // B*NSPLIT*FEAT
  unsigned* cnt = (unsigned*)(pacc + (size_t)B_ * NSPLIT * FEAT_);  // B

  qv_kernel<<<B_, 256, 0, stream>>>(input_q, W_Q, W_K, v, cnt);
  pass_kernel<<<dim3(NSPLIT, B_), 256, 0, stream>>>(input_k, ctx, v, pm, pl,
                                                    pacc, cnt, out);
}

// Round 4
// 76.064 us; speedup vs baseline: 9.8378x; 9.8378x over previous
//
#include <hip/hip_runtime.h>
#include <math.h>

#define B_    128
#define S_    2048
#define FEAT_ 512
#define DK_   64
#define NSPLIT 32
#define CHUNK  (S_ / NSPLIT)   // 64 rows per split

typedef float f32x4 __attribute__((ext_vector_type(4)));

#define SBAR() __builtin_amdgcn_sched_barrier(0)

// asm global loads: compiler's waitcnt pass does not track these, so WE own
// the vmcnt discipline (counted waits + sched_barrier per guide rule #18).
__device__ __forceinline__ void ld4(f32x4& d, const float* p) {
  asm volatile("global_load_dwordx4 %0, %1, off" : "=v"(d) : "v"(p) : "memory");
}
__device__ __forceinline__ void ld4o(f32x4& d, const float* p) {  // +1024 B
  asm volatile("global_load_dwordx4 %0, %1, off offset:1024"
               : "=v"(d) : "v"(p) : "memory");
}
#define VWAIT(N)                                              \
  do {                                                        \
    asm volatile("s_waitcnt vmcnt(" #N ")" ::: "memory");     \
    SBAR();                                                   \
  } while (0)

// issue 8 loads (4 rows x 2 halves) for rows srow, srow+4, srow+8, srow+12
#define ISSUE4(d0, d1, d2, d3, d4, d5, d6, d7, srow)                \
  do {                                                              \
    const float* r_ = base + (size_t)(srow) * FEAT_ + lane * 4;     \
    ld4(d0, r_);              ld4o(d1, r_);                         \
    ld4(d2, r_ + 4 * FEAT_);  ld4o(d3, r_ + 4 * FEAT_);             \
    ld4(d4, r_ + 8 * FEAT_);  ld4o(d5, r_ + 8 * FEAT_);             \
    ld4(d6, r_ + 12 * FEAT_); ld4o(d7, r_ + 12 * FEAT_);            \
    SBAR();                                                         \
  } while (0)

__device__ __forceinline__ float dot8(f32x4 x0, f32x4 x1, f32x4 v0, f32x4 v1) {
  float p = x0[0] * v0[0];
  p = fmaf(x0[1], v0[1], p);
  p = fmaf(x0[2], v0[2], p);
  p = fmaf(x0[3], v0[3], p);
  p = fmaf(x1[0], v1[0], p);
  p = fmaf(x1[1], v1[1], p);
  p = fmaf(x1[2], v1[2], p);
  p = fmaf(x1[3], v1[3], p);
  return p;
}

__device__ __forceinline__ float wredsum(float p) {
#pragma unroll
  for (int off = 32; off; off >>= 1) p += __shfl_xor(p, off, 64);
  return p;
}

// online-softmax update for 4 rows held in x0..x7 (row i = x(2i), x(2i+1))
__device__ __forceinline__ void compute4(
    f32x4 x0, f32x4 x1, f32x4 x2, f32x4 x3,
    f32x4 x4, f32x4 x5, f32x4 x6, f32x4 x7,
    f32x4 v0, f32x4 v1, float& m, float& l, f32x4& a0, f32x4& a1) {
  float p0 = dot8(x0, x1, v0, v1);
  float p1 = dot8(x2, x3, v0, v1);
  float p2 = dot8(x4, x5, v0, v1);
  float p3 = dot8(x6, x7, v0, v1);
  p0 = wredsum(p0);
  p1 = wredsum(p1);
  p2 = wredsum(p2);
  p3 = wredsum(p3);
  float mn = fmaxf(fmaxf(fmaxf(p0, p1), fmaxf(p2, p3)), m);
  float sc = __expf(m - mn);   // first group: exp(-inf) = 0
  float w0 = __expf(p0 - mn), w1 = __expf(p1 - mn);
  float w2 = __expf(p2 - mn), w3 = __expf(p3 - mn);
  l = fmaf(l, sc, (w0 + w1) + (w2 + w3));
#pragma unroll
  for (int j = 0; j < 4; ++j) {
    a0[j] = fmaf(w0, x0[j],
            fmaf(w1, x2[j], fmaf(w2, x4[j], fmaf(w3, x6[j], a0[j] * sc))));
    a1[j] = fmaf(w0, x1[j],
            fmaf(w1, x3[j], fmaf(w2, x5[j], fmaf(w3, x7[j], a1[j] * sc))));
  }
  m = mn;
}

// ---------------------------------------------------------------------------
// Kernel 1: v[b,f] = sum_d W_K[f,d] * (input_q[b] @ W_Q)[d]
// ---------------------------------------------------------------------------
__global__ __launch_bounds__(256) void qv_kernel(
    const float* __restrict__ input_q, const float* __restrict__ W_Q,
    const float* __restrict__ W_K, float* __restrict__ v) {
  int b = blockIdx.x;
  int tid = threadIdx.x;
  __shared__ float xq[FEAT_];
  __shared__ float part[4][DK_];
  __shared__ float qs[DK_];
  for (int f = tid; f < FEAT_; f += 256) xq[f] = input_q[b * FEAT_ + f];
  __syncthreads();
  {
    int d = tid & 63, c = tid >> 6;
    float s = 0.f;
    int f0 = c * 128;
    for (int f = f0; f < f0 + 128; ++f) s = fmaf(xq[f], W_Q[f * DK_ + d], s);
    part[c][d] = s;
  }
  __syncthreads();
  if (tid < DK_)
    qs[tid] = part[0][tid] + part[1][tid] + part[2][tid] + part[3][tid];
  __syncthreads();
  for (int f = tid; f < FEAT_; f += 256) {
    const f32x4* wk = (const f32x4*)(W_K + f * DK_);
    float s = 0.f;
#pragma unroll
    for (int d4 = 0; d4 < DK_ / 4; ++d4) {
      f32x4 w = wk[d4];
      s = fmaf(w[0], qs[d4 * 4 + 0], s);
      s = fmaf(w[1], qs[d4 * 4 + 1], s);
      s = fmaf(w[2], qs[d4 * 4 + 2], s);
      s = fmaf(w[3], qs[d4 * 4 + 3], s);
    }
    v[b * FEAT_ + f] = s;
  }
}

// ---------------------------------------------------------------------------
// Kernel 2: streaming pass. Full splits run a straight-line 4-group pipeline
// with asm loads + counted vmcnt so 8 KB/wave stays in flight during every
// compute window. Partial splits use the plain loop.
// ---------------------------------------------------------------------------
__global__ __launch_bounds__(256) void pass_kernel(
    const float* __restrict__ input_k, const int* __restrict__ ctx,
    const float* __restrict__ v, float* __restrict__ pm,
    float* __restrict__ pl, float* __restrict__ pacc) {
  int split = blockIdx.x;
  int b = blockIdx.y;
  int L = ctx[b];
  int s0 = split * CHUNK;
  int tid = threadIdx.x, wave = tid >> 6, lane = tid & 63;
  int idx = b * NSPLIT + split;

  if (s0 >= L) {  // inactive split: no pacc write; combine skips e==0
    if (tid == 0) { pm[idx] = -INFINITY; pl[idx] = 0.f; }
    return;
  }

  const float* vb = v + b * FEAT_ + lane * 4;
  f32x4 v0, v1;
  ld4(v0, vb);
  ld4o(v1, vb);
  VWAIT(0);

  float m = -INFINITY, l = 0.f;
  f32x4 a0 = {0.f, 0.f, 0.f, 0.f};
  f32x4 a1 = {0.f, 0.f, 0.f, 0.f};

  const float* base = input_k + (size_t)b * S_ * FEAT_;
  int sb = s0 + wave;

  if (L >= s0 + CHUNK) {
    // ---- full split: 16 rows/wave, straight-line depth-1 pipeline ----
    f32x4 c0, c1, c2, c3, c4, c5, c6, c7;
    f32x4 n0, n1, n2, n3, n4, n5, n6, n7;
    ISSUE4(c0, c1, c2, c3, c4, c5, c6, c7, sb);
    ISSUE4(n0, n1, n2, n3, n4, n5, n6, n7, sb + 16);
    VWAIT(8);
    compute4(c0, c1, c2, c3, c4, c5, c6, c7, v0, v1, m, l, a0, a1);
    ISSUE4(c0, c1, c2, c3, c4, c5, c6, c7, sb + 32);
    VWAIT(8);
    compute4(n0, n1, n2, n3, n4, n5, n6, n7, v0, v1, m, l, a0, a1);
    ISSUE4(n0, n1, n2, n3, n4, n5, n6, n7, sb + 48);
    VWAIT(8);
    compute4(c0, c1, c2, c3, c4, c5, c6, c7, v0, v1, m, l, a0, a1);
    VWAIT(0);
    compute4(n0, n1, n2, n3, n4, n5, n6, n7, v0, v1, m, l, a0, a1);
  } else {
    // ---- partial split (one per batch): plain loads ----
    int s1 = L;
    int s = sb;
    for (; s + 12 < s1; s += 16) {
      const float* r_ = base + (size_t)s * FEAT_ + lane * 4;
      f32x4 x0 = *(const f32x4*)(r_);
      f32x4 x1 = *(const f32x4*)(r_ + 256);
      f32x4 x2 = *(const f32x4*)(r_ + 4 * FEAT_);
      f32x4 x3 = *(const f32x4*)(r_ + 4 * FEAT_ + 256);
      f32x4 x4 = *(const f32x4*)(r_ + 8 * FEAT_);
      f32x4 x5 = *(const f32x4*)(r_ + 8 * FEAT_ + 256);
      f32x4 x6 = *(const f32x4*)(r_ + 12 * FEAT_);
      f32x4 x7 = *(const f32x4*)(r_ + 12 * FEAT_ + 256);
      compute4(x0, x1, x2, x3, x4, x5, x6, x7, v0, v1, m, l, a0, a1);
    }
    for (; s < s1; s += 4) {
      const float* r_ = base + (size_t)s * FEAT_ + lane * 4;
      f32x4 x0 = *(const f32x4*)(r_);
      f32x4 x1 = *(const f32x4*)(r_ + 256);
      float p = wredsum(dot8(x0, x1, v0, v1));
      float mn = fmaxf(m, p);
      float sc = __expf(m - mn);
      float w = __expf(p - mn);
      l = fmaf(l, sc, w);
#pragma unroll
      for (int j = 0; j < 4; ++j) {
        a0[j] = fmaf(w, x0[j], a0[j] * sc);
        a1[j] = fmaf(w, x1[j], a1[j] * sc);
      }
      m = mn;
    }
  }

  // cross-wave combine in LDS
  __shared__ float sm[4], sl[4];
  __shared__ float sa[4][FEAT_];
  if (lane == 0) { sm[wave] = m; sl[wave] = l; }
  *(f32x4*)&sa[wave][lane * 4] = a0;
  *(f32x4*)&sa[wave][256 + lane * 4] = a1;
  __syncthreads();

  float M = fmaxf(fmaxf(sm[0], sm[1]), fmaxf(sm[2], sm[3]));
  float e0 = __expf(sm[0] - M), e1 = __expf(sm[1] - M);
  float e2 = __expf(sm[2] - M), e3 = __expf(sm[3] - M);
  if (tid == 0) {
    pm[idx] = M;
    pl[idx] = e0 * sl[0] + e1 * sl[1] + e2 * sl[2] + e3 * sl[3];
  }
  for (int f = tid; f < FEAT_; f += 256)
    pacc[(size_t)idx * FEAT_ + f] =
        e0 * sa[0][f] + e1 * sa[1][f] + e2 * sa[2][f] + e3 * sa[3][f];
}

// ---------------------------------------------------------------------------
// Kernel 3: combine partials per batch, normalize, zero L==0 rows.
// ---------------------------------------------------------------------------
__global__ __launch_bounds__(256) void combine_kernel(
    const float* __restrict__ pm, const float* __restrict__ pl,
    const float* __restrict__ pacc, float* __restrict__ out) {
  int b = blockIdx.x;
  int tid = threadIdx.x;
  __shared__ float e[NSPLIT];
  __shared__ float inv_s;
  if (tid < NSPLIT) {  // lanes 0..31 of wave 0
    float mi = pm[b * NSPLIT + tid];
    float M = mi;
#pragma unroll
    for (int off = 16; off; off >>= 1) M = fmaxf(M, __shfl_xor(M, off, 64));
    float ei = (M == -INFINITY) ? 0.f : __expf(mi - M);
    e[tid] = ei;
    float lw = ei * pl[b * NSPLIT + tid];
#pragma unroll
    for (int off = 16; off; off >>= 1) lw += __shfl_xor(lw, off, 64);
    if (tid == 0) inv_s = (lw > 0.f) ? 1.f / lw : 0.f;  // L==0 -> zeros
  }
  __syncthreads();
  float inv = inv_s;
  for (int f = tid; f < FEAT_; f += 256) {
    float s = 0.f;
    for (int i = 0; i < NSPLIT; ++i)
      if (e[i] > 0.f)   // block-uniform; skips loads of never-written pacc
        s = fmaf(e[i], pacc[((size_t)(b * NSPLIT + i)) * FEAT_ + f], s);
    out[b * FEAT_ + f] = s * inv;
  }
}

extern "C" void kernel_launch(void* const* d_in, const int* in_sizes, int n_in,
                              void* d_out, int out_size, void* d_ws, size_t ws_size,
                              hipStream_t stream) {
  const float* input_k = (const float*)d_in[0];
  const float* input_q = (const float*)d_in[1];
  const int*   ctx     = (const int*)d_in[2];
  const float* W_K     = (const float*)d_in[3];
  const float* W_Q     = (const float*)d_in[4];
  float* out = (float*)d_out;

  char* ws = (char*)d_ws;
  float* v    = (float*)ws;                                   // B*FEAT
  float* pm   = (float*)(ws + (size_t)B_ * FEAT_ * sizeof(float));
  float* pl   = pm + B_ * NSPLIT;
  float* pacc = pl + B_ * NSPLIT;                             // B*NSPLIT*FEAT

  qv_kernel<<<B_, 256, 0, stream>>>(input_q, W_Q, W_K, v);
  pass_kernel<<<dim3(NSPLIT, B_), 256, 0, stream>>>(input_k, ctx, v, pm, pl, pacc);
  combine_kernel<<<B_, 256, 0, stream>>>(pm, pl, pacc, out);
}